// Round 16
// baseline (457.041 us; speedup 1.0000x reference)
//
#include <hip/hip_runtime.h>

#define DD 64
#define ROW 256        // output row stride in floats: D*(L+1)
#define CAP 32         // fixed per-head slot capacity (Poisson(10) max ~28)
#define CAPSH 5

// ---- fused build: copy entity_embed -> out slice 0; count edges per head;
//      place each edge directly at packedF[h*CAP + rank] (rank = atomicAdd
//      return). Vectorized edge pass: 4 edges/thread via int4 loads (16B
//      coalesced), int4 permpos store. Disjoint thread ranges: copy threads
//      [0, N*16), edge threads [N*16, N*16 + ceil(E/4)). rank>=CAP sets *ovf
//      (correctness fallback; never taken for Poisson(10) data). ------------
__global__ void k_build(const float* __restrict__ ent, float* __restrict__ out,
                        const int* __restrict__ heads, const int* __restrict__ rels,
                        const int* __restrict__ tails, int* __restrict__ counts,
                        int* __restrict__ ovf, int* __restrict__ permpos,
                        int* __restrict__ packedF, int n_rows, int nE) {
    int idx = blockIdx.x * blockDim.x + threadIdx.x;
    int total = n_rows * 16;                       // n_rows*16 float4s
    if (idx < total) {
        int n = idx >> 4, q = idx & 15;
        const float4* src = (const float4*)(ent + (long)n * DD);
        float4* dst = (float4*)(out + (long)n * ROW);
        dst[q] = src[q];
    } else {
        int e0 = (idx - total) << 2;
        if (e0 + 3 < nE) {
            // hot path: 4 edges, fully vectorized loads/stores
            int4 h4 = *(const int4*)(heads + e0);
            int4 r4 = *(const int4*)(rels + e0);
            int4 t4 = *(const int4*)(tails + e0);
            int4 pk;
            #pragma unroll
            for (int j = 0; j < 4; ++j) {
                int h = (&h4.x)[j];
                int rank = atomicAdd(counts + h, 1);
                (&pk.x)[j] = rank;
                if (rank < CAP) packedF[((long)h << CAPSH) + rank] = (&t4.x)[j] | ((&r4.x)[j] << 20);
                else *ovf = 1;
            }
            *(int4*)(permpos + e0) = pk;
        } else if (e0 < nE) {
            // scalar tail (never taken when nE % 4 == 0)
            for (int j = 0; j < 4 && e0 + j < nE; ++j) {
                int e = e0 + j;
                int h = heads[e];
                int rank = atomicAdd(counts + h, 1);
                permpos[e] = rank;
                if (rank < CAP) packedF[((long)h << CAPSH) + rank] = tails[e] | (rels[e] << 20);
                else *ovf = 1;
            }
        }
    }
}

// ---- fallback (only if some head overflowed CAP): single-block compact CSR
//      build. offs = exclusive scan of counts; packedF[offs[h]+permpos[e]]
//      rewritten compactly. Slow (~200us) but correct; guarded by *ovf. ------
__global__ __launch_bounds__(1024) void k_fallback(
        const int* __restrict__ heads, const int* __restrict__ rels,
        const int* __restrict__ tails, const int* __restrict__ counts,
        const int* __restrict__ ovf, int* __restrict__ offs,
        const int* __restrict__ permpos, int* __restrict__ packed,
        int n, int nE) {
    if (*ovf == 0) return;
    __shared__ int lds[1024];
    int t = threadIdx.x;
    int per = (n + 1023) / 1024;
    int lo = t * per, hi = min(lo + per, n);
    int sum = 0;
    for (int i = lo; i < hi; ++i) sum += counts[i];
    lds[t] = sum; __syncthreads();
    for (int d = 1; d < 1024; d <<= 1) {
        int u = (t >= d) ? lds[t - d] : 0;
        __syncthreads();
        lds[t] += u;
        __syncthreads();
    }
    int run = lds[t] - sum;
    for (int i = lo; i < hi; ++i) { offs[i] = run; run += counts[i]; }
    if (t == 0) offs[n] = nE;
    __syncthreads();
    for (int e = t; e < nE; e += 1024) {
        int h = heads[e];
        packed[offs[h] + permpos[e]] = tails[e] | (rels[e] << 20);
    }
}

// ---- fused KGAT layer -------------------------------------------------------
// EXACT round-9/13/15 measured artifact (101us/layer, 64 VGPR, FETCH
// 130.8MB, occupancy 38%, VALUBusy 60%). wave per head; 4 edge-groups x 16
// lanes, float4 per lane (4 dims); 2-deep software pipeline, 8 edges/iter
// (4 gathers in flight).
// mode 0 (normal): head hd's edges at [hd*CAP, hd*CAP+counts[hd]), CAP=32 ->
// descriptor footprint 12.8MB. Descriptor load issued BEFORE counts/eh4
// (p0 independent of counts in mode 0) -> hides the serial chain.
// mode 1 (overflow fallback): compact CSR via offs; chunk loop reloads.
// STRUCTURAL CONSTRAINT (rounds 1-15, eight falsified attempts): hiding the
// ~600cyc random-gather latency needs 8 waves/SIMD => <=64 VGPR; the hot
// loop's live set fills that budget exactly. ANY code growth breaks the
// cliff: 68 VGPR -> +20..23us/layer, 72 -> +38us, forced 32 -> spills ->
// +190us. Do NOT edit ANY expression in this kernel.
__global__ __launch_bounds__(256) void k_layer(
        const int* __restrict__ offs, const int* __restrict__ counts,
        const int* __restrict__ ovf, const int* __restrict__ packed,
        const float* __restrict__ hbase, const float* __restrict__ relemb,
        const float* __restrict__ W, float* __restrict__ outbase,
        int n_heads, int nE) {
    __shared__ float Wt[DD * 65];      // padded transpose: Wt[k*65+j] = W[j][k]
    __shared__ float xs[4][DD];
    const int mode = *ovf;
    for (int idx = threadIdx.x; idx < DD * DD; idx += 256)
        Wt[(idx & 63) * 65 + (idx >> 6)] = W[idx];   // 2-way bank alias: free
    __syncthreads();

    const int cap = (n_heads << CAPSH) - 1;   // clamp bound inside packedF

    int w = threadIdx.x >> 6, lane = threadIdx.x & 63;
    int g = lane >> 4, s = lane & 15;      // group 0..3, sublane 0..15

    for (int hd = blockIdx.x * 4 + w; hd < n_heads; hd += gridDim.x * 4) {
        // ---- issue descriptor load FIRST (mode 0: p0 needs no counts) ----
        int p0 = (mode == 0) ? (hd << CAPSH) : offs[hd];
        int vAll = packed[min(p0 + lane, cap)];
        int pe = (mode == 0) ? p0 + counts[hd] : offs[hd + 1];
        const float4 eh4 = *(const float4*)(hbase + (long)hd * ROW + 4 * s);
        float4 acc = make_float4(0.f, 0.f, 0.f, 0.f);
        float ssum = 0.f;

        for (int cbase = p0; cbase < pe; cbase += 64) {
            int clen = min(pe - cbase, 64);
            // vAll for this chunk already loaded (preloaded before loop /
            // at the bottom of the previous iteration)

            // prologue: stages 0 (edges g) and 1 (edges 4+g)
            int i0 = (g < clen) ? g : 0;
            int i1 = (4 + g < clen) ? 4 + g : 0;
            int v0 = __shfl(vAll, i0);
            int v1 = __shfl(vAll, i1);
            float4 tt0 = *(const float4*)(hbase + (long)(v0 & 0xFFFFF) * ROW + 4 * s);
            float4 rr0 = *(const float4*)(relemb + (v0 >> 20) * DD + 4 * s);
            float4 tt1 = *(const float4*)(hbase + (long)(v1 & 0xFFFFF) * ROW + 4 * s);
            float4 rr1 = *(const float4*)(relemb + (v1 >> 20) * DD + 4 * s);

            for (int i = 0; i < clen; i += 8) {
                // prefetch stages for i+8 (clamped; redundant tail hits cache)
                int ia = i + 8 + g;  ia = (ia < clen) ? ia : 0;
                int ib = i + 12 + g; ib = (ib < clen) ? ib : 0;
                int va = __shfl(vAll, ia);
                int vb = __shfl(vAll, ib);
                float4 tta = *(const float4*)(hbase + (long)(va & 0xFFFFF) * ROW + 4 * s);
                float4 rra = *(const float4*)(relemb + (va >> 20) * DD + 4 * s);
                float4 ttb = *(const float4*)(hbase + (long)(vb & 0xFFFFF) * ROW + 4 * s);
                float4 rrb = *(const float4*)(relemb + (vb >> 20) * DD + 4 * s);

                // ---- stage 0: edges i+g ----
                {
                    float sc = 0.f;
                    #pragma unroll
                    for (int q = 0; q < 4; ++q) {
                        float xq = (&eh4.x)[q] + (&rr0.x)[q];
                        float t = __expf(2.f * xq);
                        float th = 1.f - 2.f * __builtin_amdgcn_rcpf(t + 1.f);
                        sc += (&tt0.x)[q] * th;
                    }
                    #pragma unroll
                    for (int off = 1; off <= 8; off <<= 1) sc += __shfl_xor(sc, off);
                    float se = ((i + g) < clen) ? __expf(sc) : 0.f;
                    ssum += se;
                    acc.x += se * tt0.x; acc.y += se * tt0.y;
                    acc.z += se * tt0.z; acc.w += se * tt0.w;
                }
                // ---- stage 1: edges i+4+g ----
                {
                    float sc = 0.f;
                    #pragma unroll
                    for (int q = 0; q < 4; ++q) {
                        float xq = (&eh4.x)[q] + (&rr1.x)[q];
                        float t = __expf(2.f * xq);
                        float th = 1.f - 2.f * __builtin_amdgcn_rcpf(t + 1.f);
                        sc += (&tt1.x)[q] * th;
                    }
                    #pragma unroll
                    for (int off = 1; off <= 8; off <<= 1) sc += __shfl_xor(sc, off);
                    float se = ((i + 4 + g) < clen) ? __expf(sc) : 0.f;
                    ssum += se;
                    acc.x += se * tt1.x; acc.y += se * tt1.y;
                    acc.z += se * tt1.z; acc.w += se * tt1.w;
                }
                tt0 = tta; rr0 = rra; tt1 = ttb; rr1 = rrb;
            }

            // preload next chunk's descriptors (mode 1 only in practice)
            if (cbase + 64 < pe) vAll = packed[min(cbase + 64 + lane, cap)];
        }

        // combine the 4 groups' partial sums (lanes with equal s share dims)
        #pragma unroll
        for (int off = 16; off <= 32; off <<= 1) {
            acc.x += __shfl_xor(acc.x, off);
            acc.y += __shfl_xor(acc.y, off);
            acc.z += __shfl_xor(acc.z, off);
            acc.w += __shfl_xor(acc.w, off);
            ssum  += __shfl_xor(ssum,  off);
        }
        float inv = 1.f / (ssum + 1e-10f);
        float4 x4;
        x4.x = eh4.x + acc.x * inv;  x4.y = eh4.y + acc.y * inv;
        x4.z = eh4.z + acc.z * inv;  x4.w = eh4.w + acc.w * inv;
        if (g == 0) *(float4*)(&xs[w][4 * s]) = x4;   // wave-private slot

        // epilogue: y = leaky_relu(x @ W^T), one output dim per lane
        float y = 0.f;
        const float* xw = xs[w];
        #pragma unroll
        for (int k4 = 0; k4 < DD; k4 += 4) {
            float4 xv = *(const float4*)(xw + k4);
            y += xv.x * Wt[(k4 + 0) * 65 + lane];
            y += xv.y * Wt[(k4 + 1) * 65 + lane];
            y += xv.z * Wt[(k4 + 2) * 65 + lane];
            y += xv.w * Wt[(k4 + 3) * 65 + lane];
        }
        y = y >= 0.f ? y : 0.2f * y;
        outbase[(long)hd * ROW + lane] = y;
    }
}

extern "C" void kernel_launch(void* const* d_in, const int* in_sizes, int n_in,
                              void* d_out, int out_size, void* d_ws, size_t ws_size,
                              hipStream_t stream) {
    const int*   heads = (const int*)d_in[0];
    const int*   rels  = (const int*)d_in[1];
    const int*   tails = (const int*)d_in[2];
    const float* ent   = (const float*)d_in[3];
    const float* rel   = (const float*)d_in[4];
    const float* Ws    = (const float*)d_in[5];
    float* out = (float*)d_out;

    const int nE = in_sizes[0];
    const int N  = in_sizes[3] / DD;
    const int L  = in_sizes[5] / (DD * DD);
    const int NREL = in_sizes[4] / (L * DD);

    // workspace layout (ints): counts[N] | ovf[1] | offs[N+1] | permpos[E] |
    // packedF[N*CAP].  Total ~= 34N + E + 2 ints ~= 17.6 MB.
    int* counts  = (int*)d_ws;            // [N]
    int* ovf     = counts + N;            // [1]
    int* offs    = ovf + 1;               // [N+1]  (fallback only)
    int* permpos = offs + (N + 1);        // [E]    (fallback only)
    int* packedF = permpos + nE;          // [N*CAP]

    dim3 blk(256);
    // disjoint ranges: N*16 copy threads + ceil(nE/4) edge threads
    int fuse_total = N * 16 + (nE + 3) / 4;

    // ---- CSR-free build: memset + one fused kernel + guarded fallback ----
    hipMemsetAsync(counts, 0, (size_t)(N + 1) * sizeof(int), stream);  // counts+ovf
    k_build<<<(fuse_total + 255) / 256, blk, 0, stream>>>(
        ent, out, heads, rels, tails, counts, ovf, permpos, packedF, N, nE);
    k_fallback<<<1, 1024, 0, stream>>>(
        heads, rels, tails, counts, ovf, offs, permpos, packedF, N, nE);

    // ---- layers ----
    for (int l = 0; l < L; ++l) {
        k_layer<<<2048, blk, 0, stream>>>(
            offs, counts, ovf, packedF, out + l * DD, rel + (long)l * NREL * DD,
            Ws + (long)l * DD * DD, out + (l + 1) * DD, N, nE);
    }
}

// Round 17
// 445.028 us; speedup vs baseline: 1.0270x; 1.0270x over previous
//
#include <hip/hip_runtime.h>

#define DD 64
#define ROW 256        // output row stride in floats: D*(L+1)
#define CAP 32         // fixed per-head slot capacity (Poisson(10) max ~28)
#define CAPSH 5

// ---- fused build: copy entity_embed -> out slice 0; count edges per head;
//      place each edge directly at packedF[h*CAP + rank] (rank = atomicAdd
//      return). No scan, no scatter pass. rank>=CAP sets *ovf (correctness
//      fallback; never taken for Poisson(10) data). permpos kept for the
//      fallback path only. 1 edge/thread is OPTIMAL: the random-atomic pass
//      is per-thread-latency-bound; 4-edge int4 packing (round 16) cut MLP
//      4x and cost +11us. ----------------------------------------------------
__global__ void k_build(const float* __restrict__ ent, float* __restrict__ out,
                        const int* __restrict__ heads, const int* __restrict__ rels,
                        const int* __restrict__ tails, int* __restrict__ counts,
                        int* __restrict__ ovf, int* __restrict__ permpos,
                        int* __restrict__ packedF, int n_rows, int nE) {
    int idx = blockIdx.x * blockDim.x + threadIdx.x;
    int total = n_rows * 16;                       // n_rows*16 float4s
    if (idx < total) {
        int n = idx >> 4, q = idx & 15;
        const float4* src = (const float4*)(ent + (long)n * DD);
        float4* dst = (float4*)(out + (long)n * ROW);
        dst[q] = src[q];
    }
    if (idx < nE) {
        int h = heads[idx];
        int rank = atomicAdd(counts + h, 1);
        permpos[idx] = rank;
        if (rank < CAP) packedF[((long)h << CAPSH) + rank] = tails[idx] | (rels[idx] << 20);
        else *ovf = 1;
    }
}

// ---- fallback (only if some head overflowed CAP): single-block compact CSR
//      build. offs = exclusive scan of counts; packedF[offs[h]+permpos[e]]
//      rewritten compactly. Slow (~200us) but correct; guarded by *ovf. ------
__global__ __launch_bounds__(1024) void k_fallback(
        const int* __restrict__ heads, const int* __restrict__ rels,
        const int* __restrict__ tails, const int* __restrict__ counts,
        const int* __restrict__ ovf, int* __restrict__ offs,
        const int* __restrict__ permpos, int* __restrict__ packed,
        int n, int nE) {
    if (*ovf == 0) return;
    __shared__ int lds[1024];
    int t = threadIdx.x;
    int per = (n + 1023) / 1024;
    int lo = t * per, hi = min(lo + per, n);
    int sum = 0;
    for (int i = lo; i < hi; ++i) sum += counts[i];
    lds[t] = sum; __syncthreads();
    for (int d = 1; d < 1024; d <<= 1) {
        int u = (t >= d) ? lds[t - d] : 0;
        __syncthreads();
        lds[t] += u;
        __syncthreads();
    }
    int run = lds[t] - sum;
    for (int i = lo; i < hi; ++i) { offs[i] = run; run += counts[i]; }
    if (t == 0) offs[n] = nE;
    __syncthreads();
    for (int e = t; e < nE; e += 1024) {
        int h = heads[e];
        packed[offs[h] + permpos[e]] = tails[e] | (rels[e] << 20);
    }
}

// ---- fused KGAT layer -------------------------------------------------------
// EXACT round-9/13/15 measured artifact (101us/layer, 64 VGPR, FETCH
// 130.8MB, occupancy 38%, VALUBusy 60%; totals 444.4/447.9/445.5).
// wave per head; 4 edge-groups x 16 lanes, float4 per lane (4 dims);
// 2-deep software pipeline, 8 edges/iter (4 gathers in flight).
// mode 0 (normal): head hd's edges at [hd*CAP, hd*CAP+counts[hd]), CAP=32 ->
// descriptor footprint 12.8MB. Descriptor load issued BEFORE counts/eh4
// (p0 independent of counts in mode 0) -> hides the serial chain.
// mode 1 (overflow fallback): compact CSR via offs; chunk loop reloads.
// STRUCTURAL CONSTRAINT (rounds 1-16, nine falsified attempts): hiding the
// ~600cyc random-gather latency needs 8 waves/SIMD => <=64 VGPR; the hot
// loop's live set fills that budget exactly. ANY code growth breaks the
// cliff: 68 VGPR -> +20..23us/layer, 72 -> +38us, forced 32 -> spills ->
// +190us. Do NOT edit ANY expression in this kernel.
__global__ __launch_bounds__(256) void k_layer(
        const int* __restrict__ offs, const int* __restrict__ counts,
        const int* __restrict__ ovf, const int* __restrict__ packed,
        const float* __restrict__ hbase, const float* __restrict__ relemb,
        const float* __restrict__ W, float* __restrict__ outbase,
        int n_heads, int nE) {
    __shared__ float Wt[DD * 65];      // padded transpose: Wt[k*65+j] = W[j][k]
    __shared__ float xs[4][DD];
    const int mode = *ovf;
    for (int idx = threadIdx.x; idx < DD * DD; idx += 256)
        Wt[(idx & 63) * 65 + (idx >> 6)] = W[idx];   // 2-way bank alias: free
    __syncthreads();

    const int cap = (n_heads << CAPSH) - 1;   // clamp bound inside packedF

    int w = threadIdx.x >> 6, lane = threadIdx.x & 63;
    int g = lane >> 4, s = lane & 15;      // group 0..3, sublane 0..15

    for (int hd = blockIdx.x * 4 + w; hd < n_heads; hd += gridDim.x * 4) {
        // ---- issue descriptor load FIRST (mode 0: p0 needs no counts) ----
        int p0 = (mode == 0) ? (hd << CAPSH) : offs[hd];
        int vAll = packed[min(p0 + lane, cap)];
        int pe = (mode == 0) ? p0 + counts[hd] : offs[hd + 1];
        const float4 eh4 = *(const float4*)(hbase + (long)hd * ROW + 4 * s);
        float4 acc = make_float4(0.f, 0.f, 0.f, 0.f);
        float ssum = 0.f;

        for (int cbase = p0; cbase < pe; cbase += 64) {
            int clen = min(pe - cbase, 64);
            // vAll for this chunk already loaded (preloaded before loop /
            // at the bottom of the previous iteration)

            // prologue: stages 0 (edges g) and 1 (edges 4+g)
            int i0 = (g < clen) ? g : 0;
            int i1 = (4 + g < clen) ? 4 + g : 0;
            int v0 = __shfl(vAll, i0);
            int v1 = __shfl(vAll, i1);
            float4 tt0 = *(const float4*)(hbase + (long)(v0 & 0xFFFFF) * ROW + 4 * s);
            float4 rr0 = *(const float4*)(relemb + (v0 >> 20) * DD + 4 * s);
            float4 tt1 = *(const float4*)(hbase + (long)(v1 & 0xFFFFF) * ROW + 4 * s);
            float4 rr1 = *(const float4*)(relemb + (v1 >> 20) * DD + 4 * s);

            for (int i = 0; i < clen; i += 8) {
                // prefetch stages for i+8 (clamped; redundant tail hits cache)
                int ia = i + 8 + g;  ia = (ia < clen) ? ia : 0;
                int ib = i + 12 + g; ib = (ib < clen) ? ib : 0;
                int va = __shfl(vAll, ia);
                int vb = __shfl(vAll, ib);
                float4 tta = *(const float4*)(hbase + (long)(va & 0xFFFFF) * ROW + 4 * s);
                float4 rra = *(const float4*)(relemb + (va >> 20) * DD + 4 * s);
                float4 ttb = *(const float4*)(hbase + (long)(vb & 0xFFFFF) * ROW + 4 * s);
                float4 rrb = *(const float4*)(relemb + (vb >> 20) * DD + 4 * s);

                // ---- stage 0: edges i+g ----
                {
                    float sc = 0.f;
                    #pragma unroll
                    for (int q = 0; q < 4; ++q) {
                        float xq = (&eh4.x)[q] + (&rr0.x)[q];
                        float t = __expf(2.f * xq);
                        float th = 1.f - 2.f * __builtin_amdgcn_rcpf(t + 1.f);
                        sc += (&tt0.x)[q] * th;
                    }
                    #pragma unroll
                    for (int off = 1; off <= 8; off <<= 1) sc += __shfl_xor(sc, off);
                    float se = ((i + g) < clen) ? __expf(sc) : 0.f;
                    ssum += se;
                    acc.x += se * tt0.x; acc.y += se * tt0.y;
                    acc.z += se * tt0.z; acc.w += se * tt0.w;
                }
                // ---- stage 1: edges i+4+g ----
                {
                    float sc = 0.f;
                    #pragma unroll
                    for (int q = 0; q < 4; ++q) {
                        float xq = (&eh4.x)[q] + (&rr1.x)[q];
                        float t = __expf(2.f * xq);
                        float th = 1.f - 2.f * __builtin_amdgcn_rcpf(t + 1.f);
                        sc += (&tt1.x)[q] * th;
                    }
                    #pragma unroll
                    for (int off = 1; off <= 8; off <<= 1) sc += __shfl_xor(sc, off);
                    float se = ((i + 4 + g) < clen) ? __expf(sc) : 0.f;
                    ssum += se;
                    acc.x += se * tt1.x; acc.y += se * tt1.y;
                    acc.z += se * tt1.z; acc.w += se * tt1.w;
                }
                tt0 = tta; rr0 = rra; tt1 = ttb; rr1 = rrb;
            }

            // preload next chunk's descriptors (mode 1 only in practice)
            if (cbase + 64 < pe) vAll = packed[min(cbase + 64 + lane, cap)];
        }

        // combine the 4 groups' partial sums (lanes with equal s share dims)
        #pragma unroll
        for (int off = 16; off <= 32; off <<= 1) {
            acc.x += __shfl_xor(acc.x, off);
            acc.y += __shfl_xor(acc.y, off);
            acc.z += __shfl_xor(acc.z, off);
            acc.w += __shfl_xor(acc.w, off);
            ssum  += __shfl_xor(ssum,  off);
        }
        float inv = 1.f / (ssum + 1e-10f);
        float4 x4;
        x4.x = eh4.x + acc.x * inv;  x4.y = eh4.y + acc.y * inv;
        x4.z = eh4.z + acc.z * inv;  x4.w = eh4.w + acc.w * inv;
        if (g == 0) *(float4*)(&xs[w][4 * s]) = x4;   // wave-private slot

        // epilogue: y = leaky_relu(x @ W^T), one output dim per lane
        float y = 0.f;
        const float* xw = xs[w];
        #pragma unroll
        for (int k4 = 0; k4 < DD; k4 += 4) {
            float4 xv = *(const float4*)(xw + k4);
            y += xv.x * Wt[(k4 + 0) * 65 + lane];
            y += xv.y * Wt[(k4 + 1) * 65 + lane];
            y += xv.z * Wt[(k4 + 2) * 65 + lane];
            y += xv.w * Wt[(k4 + 3) * 65 + lane];
        }
        y = y >= 0.f ? y : 0.2f * y;
        outbase[(long)hd * ROW + lane] = y;
    }
}

extern "C" void kernel_launch(void* const* d_in, const int* in_sizes, int n_in,
                              void* d_out, int out_size, void* d_ws, size_t ws_size,
                              hipStream_t stream) {
    const int*   heads = (const int*)d_in[0];
    const int*   rels  = (const int*)d_in[1];
    const int*   tails = (const int*)d_in[2];
    const float* ent   = (const float*)d_in[3];
    const float* rel   = (const float*)d_in[4];
    const float* Ws    = (const float*)d_in[5];
    float* out = (float*)d_out;

    const int nE = in_sizes[0];
    const int N  = in_sizes[3] / DD;
    const int L  = in_sizes[5] / (DD * DD);
    const int NREL = in_sizes[4] / (L * DD);

    // workspace layout (ints): counts[N] | ovf[1] | offs[N+1] | permpos[E] |
    // packedF[N*CAP].  Total ~= 34N + E + 2 ints ~= 17.6 MB.
    int* counts  = (int*)d_ws;            // [N]
    int* ovf     = counts + N;            // [1]
    int* offs    = ovf + 1;               // [N+1]  (fallback only)
    int* permpos = offs + (N + 1);        // [E]    (fallback only)
    int* packedF = permpos + nE;          // [N*CAP]

    dim3 blk(256);
    int fuse_total = max(N * 16, nE);

    // ---- CSR-free build: memset + one fused kernel + guarded fallback ----
    hipMemsetAsync(counts, 0, (size_t)(N + 1) * sizeof(int), stream);  // counts+ovf
    k_build<<<(fuse_total + 255) / 256, blk, 0, stream>>>(
        ent, out, heads, rels, tails, counts, ovf, permpos, packedF, N, nE);
    k_fallback<<<1, 1024, 0, stream>>>(
        heads, rels, tails, counts, ovf, offs, permpos, packedF, N, nE);

    // ---- layers ----
    for (int l = 0; l < L; ++l) {
        k_layer<<<2048, blk, 0, stream>>>(
            offs, counts, ovf, packedF, out + l * DD, rel + (long)l * NREL * DD,
            Ws + (long)l * DD * DD, out + (l + 1) * DD, N, nE);
    }
}